// Round 1
// 150.903 us; speedup vs baseline: 1.0385x; 1.0385x over previous
//
#include <hip/hip_runtime.h>

// Length regulator: out[b, p, :] = att_out[b, idx(b,p), :] for p < total[b], else 0.
// idx(b,p) = upper_bound(csum[b], p), csum = cumsum(round(duration*alpha)).
//
// B=32, L=256, D=512, MAX_LEN=2048. Output 128 MB fp32 -> pure write-stream, memory-bound.
//
// v2 design notes (vs 156.7us baseline whose kernel part was ~73us, ~1.8 TB/s):
//  - scan: shfl-based wave scan, 2 barriers (was 17-barrier Hillis-Steele)
//  - searches hoisted out of copy loop: per-block idx_tab[32] built once by 32 threads
//    (was: 8-deep dependent ds_read binary-search chain PER ROW PASS = latency wall)
//  - copy loop: 16 independent {broadcast ds_read, global load, cndmask, store} units,
//    branchless (clamped srow), fully unrolled -> store pipe stays fed
//  - XCD-aware block remap: lin%8 = XCD (round-robin dispatch); give each XCD 4 whole
//    batches so gather reads stay in that XCD's 4MB L2 (4 x 512KB = 2MB)

constexpr int B = 32;
constexpr int L = 256;
constexpr int D = 512;            // floats per row = 128 float4
constexpr int MAX_LEN = 2048;
constexpr int POS = 32;           // output positions per block
constexpr int THREADS = 256;      // 2 rows in flight (128 float4 lanes per row)

__global__ __launch_bounds__(THREADS) void length_regulator_kernel(
    const float* __restrict__ att_out,   // (B, L, D)
    const float* __restrict__ duration,  // (B, L)
    const int*   __restrict__ alpha_p,   // scalar
    float*       __restrict__ out)       // (B, MAX_LEN, D)
{
    __shared__ int csum[L];
    __shared__ int idx_tab[POS];
    __shared__ int wsum[4];

    const int tid  = threadIdx.x;
    const int lane = tid & 63;
    const int wave = tid >> 6;

    // XCD-aware remap: linear block id round-robins over 8 XCDs (measured mapping).
    // Assign each XCD 4 whole batches -> its gather reads L2-fit. 2048 % 8 == 0 -> bijective.
    const int lin      = blockIdx.y * gridDim.x + blockIdx.x;   // 0..2047
    const int xcd      = lin & 7;
    const int slot     = lin >> 3;                              // 0..255
    const int b        = xcd * (B / 8) + (slot >> 6);           // 4 batches per XCD
    const int pos_base = (slot & 63) * POS;

    const float alpha = (float)alpha_p[0];

    // ---- cumulative sum of r = round-half-even(duration*alpha), 2 barriers ----
    int v = (int)rintf(duration[b * L + tid] * alpha);
    int x = v;
    #pragma unroll
    for (int off = 1; off < 64; off <<= 1) {
        int y = __shfl_up(x, off);
        x += (lane >= off) ? y : 0;
    }
    if (lane == 63) wsum[wave] = x;
    __syncthreads();
    const int w0 = wsum[0], w1 = wsum[1], w2 = wsum[2], w3 = wsum[3];
    const int total = w0 + w1 + w2 + w3;
    const int woff = (wave > 0 ? w0 : 0) + (wave > 1 ? w1 : 0) + (wave > 2 ? w2 : 0);
    csum[tid] = x + woff;
    __syncthreads();

    // ---- per-block idx table: 32 branchless searches, done ONCE (1 barrier) ----
    if (tid < POS) {
        const int p = pos_base + tid;
        int lo = 0;                       // count of csum entries <= p == upper_bound
        #pragma unroll
        for (int step = 128; step >= 1; step >>= 1) {
            const int nxt = lo + step;
            if (nxt <= L && csum[nxt - 1] <= p) lo = nxt;
        }
        idx_tab[tid] = min(lo, L - 1);    // clamp (also covers p >= total)
    }
    __syncthreads();

    // ---- copy: 16 independent passes x 2 rows x 128 lanes x float4 ----
    const int lane_r = tid & 127;
    const int rowsel = tid >> 7;          // 0 or 1

    const float4* __restrict__ src4 = (const float4*)(att_out + (size_t)b * L * D);
    float4*       __restrict__ dst4 =
        (float4*)(out + ((size_t)b * MAX_LEN + pos_base) * D);

    #pragma unroll
    for (int i = 0; i < POS; i += 2) {
        const int rp = i + rowsel;                    // row within block
        const int p  = pos_base + rp;
        const int srow = idx_tab[rp];                 // broadcast LDS read (wave-uniform)
        float4 t = src4[(size_t)srow * (D / 4) + lane_r];   // clamped -> always in-bounds
        float4 val;
        const bool keep = (p < total);                // wave-uniform
        val.x = keep ? t.x : 0.f;
        val.y = keep ? t.y : 0.f;
        val.z = keep ? t.z : 0.f;
        val.w = keep ? t.w : 0.f;
        dst4[(size_t)rp * (D / 4) + lane_r] = val;
    }
}

extern "C" void kernel_launch(void* const* d_in, const int* in_sizes, int n_in,
                              void* d_out, int out_size, void* d_ws, size_t ws_size,
                              hipStream_t stream) {
    const float* att_out  = (const float*)d_in[0];
    const float* duration = (const float*)d_in[1];
    const int*   alpha    = (const int*)d_in[2];
    float*       out      = (float*)d_out;

    dim3 grid(MAX_LEN / POS, B);   // (64, 32) = 2048 blocks = 256 CUs x 8 resident
    dim3 block(THREADS);
    length_regulator_kernel<<<grid, block, 0, stream>>>(att_out, duration, alpha, out);
}